// Round 6
// baseline (350.522 us; speedup 1.0000x reference)
//
#include <hip/hip_runtime.h>
#include <math.h>

#define TOKENS 8192
#define DDIM   4096
#define NE     16
#define NOUT   32

#define OUT_BAL  32768
#define OUT_LOAD 32769
#define OUT_IMP  32785
#define OUT_IDX  32801

// ---------------------------------------------------------------------------
// Kernel A: fused tall-skinny GEMM, all-register operands, ZERO LDS.
// Wave = 8 tokens x 8 k-quads (lane = (tau, kq)). Lane computes
// acc[o] = sum over its k-quads of x[t][k]*W[o][k] for ALL 32 outputs;
// kq-partials reduced by a 3-step shfl_xor butterfly at the end.
// x: 1 coalesced dwordx4 per lane per 32-k slab, prefetched one 4-slab
// group (~1024 cyc) ahead -> HBM latency hidden. w: 32 dwordx4 per slab,
// 8-distinct-addr broadcast (L1/L2-hot), reloaded right after last use.
// K split cs ways -> P[t][c][o]; grid = 1024*cs/4 blocks of 256.
// ---------------------------------------------------------------------------
__global__ __launch_bounds__(256, 2) void gate_gemm(
    const float* __restrict__ x,
    const float* __restrict__ Wg1,
    const float* __restrict__ Wn,
    float* __restrict__ P,        // [TOKENS][cs][NOUT]
    int lcs, int nslab)
{
    const int tid  = threadIdx.x;
    const int lane = tid & 63;
    const int wid  = blockIdx.x * 4 + (tid >> 6);
    const int cs   = 1 << lcs;
    const int c    = wid & (cs - 1);
    const int t8   = wid >> lcs;
    const int kq   = lane & 7;
    const int tau  = lane >> 3;
    const int t    = t8 * 8 + tau;
    const int kbase = c * (nslab * 32);

    const float* xp = x + (size_t)t * DDIM + kbase + 4 * kq;

    float acc[NOUT];
#pragma unroll
    for (int o = 0; o < NOUT; ++o) acc[o] = 0.0f;

    // current group's 4 slab-quads of x
    float4 xq0 = *(const float4*)(xp + 0 * 32);
    float4 xq1 = *(const float4*)(xp + 1 * 32);
    float4 xq2 = *(const float4*)(xp + 2 * 32);
    float4 xq3 = *(const float4*)(xp + 3 * 32);

    // w quads for slab 0 (128 VGPRs, the big register block)
    float4 wq[NOUT];
#pragma unroll
    for (int o = 0; o < NOUT; ++o) {
        const float* wr = (o < NE) ? (Wg1 + (size_t)o * DDIM)
                                   : (Wn  + (size_t)(o - NE) * DDIM);
        wq[o] = *(const float4*)(wr + kbase + 4 * kq);
    }

    const int ngroups = nslab >> 2;
    for (int g = 0; g < ngroups; ++g) {
        // issue NEXT group's x loads early (clamped re-read on last group)
        const int gn = (g + 1 < ngroups) ? g + 1 : g;
        const float4 xn0 = *(const float4*)(xp + (gn * 4 + 0) * 32);
        const float4 xn1 = *(const float4*)(xp + (gn * 4 + 1) * 32);
        const float4 xn2 = *(const float4*)(xp + (gn * 4 + 2) * 32);
        const float4 xn3 = *(const float4*)(xp + (gn * 4 + 3) * 32);

#pragma unroll
        for (int ss = 0; ss < 4; ++ss) {
            const float4 xc = (ss == 0) ? xq0 : (ss == 1) ? xq1
                            : (ss == 2) ? xq2 : xq3;
            const int sidx = g * 4 + ss;
            // next slab's w offset (last slab: harmless in-bounds re-read)
            const int noff = kbase + 4 * kq
                           + ((sidx + 1 < nslab) ? (sidx + 1) : sidx) * 32;
#pragma unroll
            for (int o = 0; o < NOUT; ++o) {
                const float4 f = wq[o];
                acc[o] = fmaf(f.x, xc.x, acc[o]);
                acc[o] = fmaf(f.y, xc.y, acc[o]);
                acc[o] = fmaf(f.z, xc.z, acc[o]);
                acc[o] = fmaf(f.w, xc.w, acc[o]);
                const float* wr = (o < NE) ? (Wg1 + (size_t)o * DDIM)
                                           : (Wn  + (size_t)(o - NE) * DDIM);
                wq[o] = *(const float4*)(wr + noff);   // reload right after use
            }
        }
        xq0 = xn0; xq1 = xn1; xq2 = xn2; xq3 = xn3;
    }

    // --- butterfly reduce over kq (recursive halving, static reg indices) ---
    // After step r, lane keeps the output half selected by its kq bit r.
    const int sel1 = kq & 1, sel2 = (kq >> 1) & 1, sel3 = kq >> 2;
    float l1[16];
#pragma unroll
    for (int i = 0; i < 16; ++i) {
        const float mine = sel1 ? acc[16 + i] : acc[i];
        const float send = sel1 ? acc[i]      : acc[16 + i];
        l1[i] = mine + __shfl_xor(send, 1, 64);
    }
    float l2[8];
#pragma unroll
    for (int i = 0; i < 8; ++i) {
        const float mine = sel2 ? l1[8 + i] : l1[i];
        const float send = sel2 ? l1[i]     : l1[8 + i];
        l2[i] = mine + __shfl_xor(send, 2, 64);
    }
    float l3[4];
#pragma unroll
    for (int i = 0; i < 4; ++i) {
        const float mine = sel3 ? l2[4 + i] : l2[i];
        const float send = sel3 ? l2[i]     : l2[4 + i];
        l3[i] = mine + __shfl_xor(send, 4, 64);
    }
    // lane's final quad is o = obase..obase+3 ; union over kq = 0..31 exactly
    const int obase = sel1 * 16 + sel2 * 8 + sel3 * 4;
    float4 r; r.x = l3[0]; r.y = l3[1]; r.z = l3[2]; r.w = l3[3];
    *(float4*)(P + ((size_t)t * cs + c) * NOUT + obase) = r;
}

// ---------------------------------------------------------------------------
// Kernel B: epilogue, 16 lanes per token (lane = expert).
// P rows [t][c][o] contiguous per token -> c-loop loads coalesce.
// ---------------------------------------------------------------------------
__global__ __launch_bounds__(256) void gate_epilogue(
    const float* __restrict__ P,
    const float* __restrict__ noise,
    const float* __restrict__ Wg2,
    float* __restrict__ out,
    float* __restrict__ gacc,   // [0..15] importance, [16..31] load
    int cs)
{
    __shared__ float s_imp[NE];
    __shared__ float s_load[NE];

    const int tid = threadIdx.x;
    if (tid < NE) { s_imp[tid] = 0.0f; s_load[tid] = 0.0f; }
    __syncthreads();

    const int t     = blockIdx.x * 16 + (tid >> 4);
    const int e     = tid & 15;
    const int lane  = tid & 63;
    const int gbase = lane & 48;   // 16-lane group base within wave

    const float* pr = P + (size_t)t * cs * NOUT;
    float g1 = 0.0f, nn = 0.0f;
#pragma unroll 8
    for (int c = 0; c < cs; ++c) {
        g1 += pr[c * NOUT + e];
        nn += pr[c * NOUT + NE + e];
    }

    float w2r[16];
#pragma unroll
    for (int r = 0; r < 4; ++r) {
        const float4 w = *(const float4*)(Wg2 + e * NE + r * 4);
        w2r[r * 4 + 0] = w.x; w2r[r * 4 + 1] = w.y;
        w2r[r * 4 + 2] = w.z; w2r[r * 4 + 3] = w.w;
    }

    const float h = tanhf(g1);
    float gate = 0.0f;
#pragma unroll
    for (int j = 0; j < 16; ++j) {
        const float hj = __shfl(h, gbase + j, 64);
        gate = fmaf(w2r[j], hj, gate);
    }

    const float nv  = noise[(size_t)t * NE + e];
    const float sp  = fmaxf(nn, 0.0f) + log1pf(expf(-fabsf(nn)));
    const float ncv = sp + 0.01f;
    const float ln  = nv * ncv;
    const float lg  = gate + ln;

    // top-5 across 16-lane group: (val,idx) butterfly, lowest-idx tie-break
    float tv[5]; int tix[5];
    bool masked = false;
#pragma unroll
    for (int r = 0; r < 5; ++r) {
        float cv = masked ? -INFINITY : lg;
        int   ci = e;
#pragma unroll
        for (int st = 1; st < 16; st <<= 1) {
            const float ov = __shfl_xor(cv, st, 64);
            const int   oi = __shfl_xor(ci, st, 64);
            const bool take = (ov > cv) || (ov == cv && oi < ci);
            cv = take ? ov : cv;
            ci = take ? oi : ci;
        }
        tv[r] = cv; tix[r] = ci;
        masked = masked || (e == ci);
    }

    const float m = tv[0];
    const float ssum = expf(tv[0] - m) + expf(tv[1] - m)
                     + expf(tv[2] - m) + expf(tv[3] - m);
    const float inv = 1.0f / ssum;

    if (e < 4) {
        const float myv = (e == 0) ? tv[0] : (e == 1) ? tv[1] : (e == 2) ? tv[2] : tv[3];
        const int   myi = (e == 0) ? tix[0] : (e == 1) ? tix[1] : (e == 2) ? tix[2] : tix[3];
        const float sc  = expf(myv - m) * inv;
        out[(size_t)t * 4 + e]           = sc;
        out[OUT_IDX + (size_t)t * 4 + e] = (float)myi;
        atomicAdd(&s_imp[myi], sc);
    }

    const float thr = (ln > tv[4]) ? tv[4] : tv[3];
    const float pr2 = 0.5f * erfcf((thr - gate) * 0.70710678118654752440f / ncv);
    atomicAdd(&s_load[e], pr2);
    __syncthreads();

    if (tid < NE)          atomicAdd(gacc + tid, s_imp[tid]);
    else if (tid < 2 * NE) atomicAdd(gacc + tid, s_load[tid - NE]);
}

// ---------------------------------------------------------------------------
// Kernel C: balance loss + copy-out of load/importance.
// ---------------------------------------------------------------------------
__global__ void gate_finalize(const float* __restrict__ gacc, float* __restrict__ out)
{
    const int tid = threadIdx.x;
    if (tid == 0) {
        double mi = 0.0, ml = 0.0;
        for (int e = 0; e < NE; ++e) { mi += gacc[e]; ml += gacc[NE + e]; }
        mi /= NE; ml /= NE;
        double vi = 0.0, vl = 0.0;
        for (int e = 0; e < NE; ++e) {
            const double di = gacc[e] - mi;      vi += di * di;
            const double dl = gacc[NE + e] - ml; vl += dl * dl;
        }
        vi /= (NE - 1); vl /= (NE - 1);
        const double cvi = vi / (mi * mi + 1e-10);
        const double cvl = vl / (ml * ml + 1e-10);
        out[OUT_BAL] = (float)(0.01 * (cvi + cvl));
    }
    if (tid < NE) {
        out[OUT_LOAD + tid] = gacc[NE + tid];  // load
        out[OUT_IMP  + tid] = gacc[tid];       // importance
    }
}

extern "C" void kernel_launch(void* const* d_in, const int* in_sizes, int n_in,
                              void* d_out, int out_size, void* d_ws, size_t ws_size,
                              hipStream_t stream)
{
    const float* x     = (const float*)d_in[0];
    const float* noise = (const float*)d_in[1];
    const float* Wg1   = (const float*)d_in[2];
    const float* Wg2   = (const float*)d_in[3];
    const float* Wn    = (const float*)d_in[4];
    float* out = (float*)d_out;

    // ws layout: gacc[64 floats pad] | P[TOKENS][cs][NOUT]
    float* gacc = (float*)d_ws;
    float* P    = gacc + 64;

    // largest power-of-two K-split that fits ws (never write past ws_size)
    int cs = 16, lcs = 4;
    while (cs > 1 && 256 + (size_t)cs * TOKENS * NOUT * sizeof(float) > ws_size) {
        cs >>= 1; lcs -= 1;
    }
    const int nslab = DDIM / (cs * 32);   // 32-k slabs per chunk (mult of 4)

    hipMemsetAsync(gacc, 0, 32 * sizeof(float), stream);

    const int nblocks = (TOKENS / 8) * cs / 4;      // 4 waves per block
    gate_gemm<<<nblocks, 256, 0, stream>>>(x, Wg1, Wn, P, lcs, nslab);
    gate_epilogue<<<TOKENS / 16, 256, 0, stream>>>(P, noise, Wg2, out, gacc, cs);
    gate_finalize<<<1, 64, 0, stream>>>(gacc, out);
}